// Round 1
// baseline (276.152 us; speedup 1.0000x reference)
//
#include <hip/hip_runtime.h>
#include <cstdint>
#include <cstddef>

#define E_TOT 32768
#define HD    512
#define NR    3

typedef __attribute__((ext_vector_type(8))) short short8;
typedef __attribute__((ext_vector_type(4))) float f32x4;

static __device__ __forceinline__ unsigned short f2bf(float f) {
  union { float f; unsigned int u; } x; x.f = f;
  unsigned int u = x.u;
  return (unsigned short)((u + 0x7fffu + ((u >> 16) & 1u)) >> 16);  // RNE
}

static __device__ __forceinline__ void gload_lds16(const void* g, void* l) {
  __builtin_amdgcn_global_load_lds(
      (const __attribute__((address_space(1))) unsigned int*)g,
      (__attribute__((address_space(3))) unsigned int*)l, 16, 0, 0);
}

// ---------------- prep kernels ----------------

__global__ void k_init(int* ctrl) {
  if (threadIdx.x < 16) ctrl[threadIdx.x] = 0;
}

__global__ void k_hist(const int* __restrict__ roles, int* __restrict__ ctrl) {
  int e = blockIdx.x * 256 + threadIdx.x;
  int lane = threadIdx.x & 63;
  int role = roles[e];
#pragma unroll
  for (int r = 0; r < NR; ++r) {
    unsigned long long m = __ballot(role == r);
    if (lane == 0 && m) atomicAdd(&ctrl[r], (int)__popcll(m));
  }
}

__global__ void k_scan(int* ctrl) {
  if (threadIdx.x == 0 && blockIdx.x == 0) {
    int off = 0;
#pragma unroll
    for (int r = 0; r < NR; ++r) { ctrl[4 + r] = off; ctrl[9 + r] = off; off += ctrl[r]; }
    ctrl[4 + NR] = off;
  }
}

__global__ void k_scatter(const int* __restrict__ roles, int* __restrict__ ctrl,
                          int* __restrict__ perm) {
  int e = blockIdx.x * 256 + threadIdx.x;
  int lane = threadIdx.x & 63;
  int role = roles[e];
#pragma unroll
  for (int r = 0; r < NR; ++r) {
    unsigned long long m = __ballot(role == r);
    if (!m) continue;
    int leader = __ffsll((unsigned long long)m) - 1;
    int base = 0;
    if (lane == leader) base = atomicAdd(&ctrl[9 + r], (int)__popcll(m));
    base = __shfl(base, leader);
    if (role == r) {
      int rank = (int)__popcll(m & ((1ull << lane) - 1ull));
      perm[base + rank] = e;
    }
  }
}

// convert this layer's W,U,P1,P2 slices to bf16: dst = 4 consecutive [NR*HD*HD] arrays
__global__ void k_convw(const float* __restrict__ W, const float* __restrict__ U,
                        const float* __restrict__ P1, const float* __restrict__ P2,
                        const int* __restrict__ dlayer, short* __restrict__ dst) {
  const int per = NR * HD * HD;
  const int which = blockIdx.y;
  const float* src = (which == 0) ? W : (which == 1) ? U : (which == 2) ? P1 : P2;
  src += (size_t)dlayer[0] * per;
  short* d = dst + (size_t)which * per;
  int i = (blockIdx.x * 256 + threadIdx.x) * 4;
  if (i >= per) return;
  float4 v = *(const float4*)(src + i);
  short4 o;
  o.x = (short)f2bf(v.x); o.y = (short)f2bf(v.y);
  o.z = (short)f2bf(v.z); o.w = (short)f2bf(v.w);
  *(short4*)(d + i) = o;
}

// ---------------- GEMM kernels ----------------
// Tile: BM=128, BN=128, BK=64, 256 threads (4 waves, 2x2), 16x16x32 bf16 MFMA.
// A-frag: lane holds A[row=lane&15][k = kk + (lane>>4)*8 + 0..7] (8 contiguous bf16)
// D-frag: col = lane&15, row = (lane>>4)*4 + reg   [m89/m91-verified layout]

// G1: h = (gather(v)@W^T + wb) * (gather(r)@U^T + ub), sorted rows, bf16 out
__global__ __launch_bounds__(256, 2) void k_g1(
    const float* __restrict__ v, const float* __restrict__ r,
    const short* __restrict__ Wbf, const short* __restrict__ Ubf,
    const float* __restrict__ Wb, const float* __restrict__ Ub,
    const int* __restrict__ dlayer, const int* __restrict__ ctrl,
    const int* __restrict__ perm, short* __restrict__ hout) {
  __shared__ short Av[128 * 64];
  __shared__ short Ar[128 * 64];
  __shared__ short Bw[128 * 64];
  __shared__ short Bu[128 * 64];

  const int role = blockIdx.z;
  const int mStart = ctrl[4 + role];
  const int mEnd = ctrl[5 + role];
  const int m0 = mStart + blockIdx.x * 128;
  if (m0 >= mEnd) return;
  const int n0 = blockIdx.y * 128;

  const int tid = threadIdx.x;
  const int lane = tid & 63;
  const int wv = tid >> 6;
  const int wr = wv >> 1, wc = wv & 1;
  const int trow0 = tid >> 3;   // staging row (0..31), +32 per issue
  const int chunk = tid & 7;    // 8-bf16 chunk within 64-wide row

  const short* Wrole = Wbf + (size_t)role * HD * HD;
  const short* Urole = Ubf + (size_t)role * HD * HD;

  const float* vsrc[4];
  const float* rsrc[4];
#pragma unroll
  for (int i = 0; i < 4; ++i) {
    int mrow = m0 + trow0 + 32 * i;
    if (mrow >= mEnd) mrow = mEnd - 1;   // clamp: pad rows duplicate last valid row
    const int g = perm[mrow];
    vsrc[i] = v + (size_t)g * HD + chunk * 8;
    rsrc[i] = r + (size_t)g * HD + chunk * 8;
  }

  f32x4 accv[4][4];
  f32x4 accr[4][4];
#pragma unroll
  for (int a = 0; a < 4; ++a)
#pragma unroll
    for (int b = 0; b < 4; ++b) { accv[a][b] = (f32x4)0.f; accr[a][b] = (f32x4)0.f; }

  for (int k0 = 0; k0 < HD; k0 += 64) {
    __syncthreads();  // LDS free from previous compute
    // A tiles: reg-staged f32 -> bf16 -> ds_write_b128
#pragma unroll
    for (int i = 0; i < 4; ++i) {
      const int row = trow0 + 32 * i;
      const float4 a0 = *(const float4*)(vsrc[i] + k0);
      const float4 a1 = *(const float4*)(vsrc[i] + k0 + 4);
      const float4 b0 = *(const float4*)(rsrc[i] + k0);
      const float4 b1 = *(const float4*)(rsrc[i] + k0 + 4);
      short8 pa, pb;
      pa[0] = (short)f2bf(a0.x); pa[1] = (short)f2bf(a0.y);
      pa[2] = (short)f2bf(a0.z); pa[3] = (short)f2bf(a0.w);
      pa[4] = (short)f2bf(a1.x); pa[5] = (short)f2bf(a1.y);
      pa[6] = (short)f2bf(a1.z); pa[7] = (short)f2bf(a1.w);
      pb[0] = (short)f2bf(b0.x); pb[1] = (short)f2bf(b0.y);
      pb[2] = (short)f2bf(b0.z); pb[3] = (short)f2bf(b0.w);
      pb[4] = (short)f2bf(b1.x); pb[5] = (short)f2bf(b1.y);
      pb[6] = (short)f2bf(b1.z); pb[7] = (short)f2bf(b1.w);
      *(short8*)&Av[row * 64 + chunk * 8] = pa;
      *(short8*)&Ar[row * 64 + chunk * 8] = pb;
    }
    // B tiles (bf16 weights): async global->LDS, width 16
#pragma unroll
    for (int i = 0; i < 4; ++i) {
      const int row = trow0 + 32 * i;
      gload_lds16(Wrole + (size_t)(n0 + row) * HD + k0 + chunk * 8,
                  (char*)Bw + i * 4096 + wv * 1024);
      gload_lds16(Urole + (size_t)(n0 + row) * HD + k0 + chunk * 8,
                  (char*)Bu + i * 4096 + wv * 1024);
    }
    __syncthreads();  // drains vmcnt+lgkmcnt
#pragma unroll
    for (int kk = 0; kk < 64; kk += 32) {
      const int krow = lane & 15;
      const int koff = kk + ((lane >> 4) << 3);
      short8 fav[4], far_[4], fbw[4], fbu[4];
#pragma unroll
      for (int mi = 0; mi < 4; ++mi) {
        fav[mi]  = *(const short8*)&Av[(wr * 64 + mi * 16 + krow) * 64 + koff];
        far_[mi] = *(const short8*)&Ar[(wr * 64 + mi * 16 + krow) * 64 + koff];
      }
#pragma unroll
      for (int ni = 0; ni < 4; ++ni) {
        fbw[ni] = *(const short8*)&Bw[(wc * 64 + ni * 16 + krow) * 64 + koff];
        fbu[ni] = *(const short8*)&Bu[(wc * 64 + ni * 16 + krow) * 64 + koff];
      }
#pragma unroll
      for (int mi = 0; mi < 4; ++mi)
#pragma unroll
        for (int ni = 0; ni < 4; ++ni) {
          accv[mi][ni] = __builtin_amdgcn_mfma_f32_16x16x32_bf16(fav[mi], fbw[ni], accv[mi][ni], 0, 0, 0);
          accr[mi][ni] = __builtin_amdgcn_mfma_f32_16x16x32_bf16(far_[mi], fbu[ni], accr[mi][ni], 0, 0, 0);
        }
    }
  }

  const int ld = dlayer[0];
  const float* wb = Wb + ((size_t)ld * NR + role) * HD + n0;
  const float* ub = Ub + ((size_t)ld * NR + role) * HD + n0;
#pragma unroll
  for (int ni = 0; ni < 4; ++ni) {
    const int col = wc * 64 + ni * 16 + (lane & 15);
    const float bw_ = wb[col];
    const float bu_ = ub[col];
#pragma unroll
    for (int mi = 0; mi < 4; ++mi) {
      const int rbase = wr * 64 + mi * 16 + ((lane >> 4) << 2);
#pragma unroll
      for (int j = 0; j < 4; ++j) {
        const int gr = m0 + rbase + j;
        if (gr < mEnd) {
          const float hval = (accv[mi][ni][j] + bw_) * (accr[mi][ni][j] + bu_);
          hout[(size_t)gr * HD + n0 + col] = (short)f2bf(hval);
        }
      }
    }
  }
}

// G2 (MODE 1): t = relu(h@P1^T + b1) -> bf16, sorted rows
// G3 (MODE 2): out[perm[row]] = t@P2^T + b2 -> f32
template <int MODE>
__global__ __launch_bounds__(256, 2) void k_g23(
    const short* __restrict__ Ain, const short* __restrict__ Ball,
    const float* __restrict__ biasAll, const int* __restrict__ dlayer,
    const int* __restrict__ ctrl, const int* __restrict__ perm,
    short* __restrict__ tout, float* __restrict__ fout) {
  __shared__ short As[128 * 64];
  __shared__ short Bs[128 * 64];

  const int role = blockIdx.z;
  const int mStart = ctrl[4 + role];
  const int mEnd = ctrl[5 + role];
  const int m0 = mStart + blockIdx.x * 128;
  if (m0 >= mEnd) return;
  const int n0 = blockIdx.y * 128;

  const int tid = threadIdx.x;
  const int lane = tid & 63;
  const int wv = tid >> 6;
  const int wr = wv >> 1, wc = wv & 1;
  const int trow0 = tid >> 3;
  const int chunk = tid & 7;

  const short* Brole = Ball + (size_t)role * HD * HD;

  const short* asrc[4];
#pragma unroll
  for (int i = 0; i < 4; ++i) {
    int mrow = m0 + trow0 + 32 * i;
    if (mrow >= mEnd) mrow = mEnd - 1;
    asrc[i] = Ain + (size_t)mrow * HD + chunk * 8;
  }

  f32x4 acc[4][4];
#pragma unroll
  for (int a = 0; a < 4; ++a)
#pragma unroll
    for (int b = 0; b < 4; ++b) acc[a][b] = (f32x4)0.f;

  for (int k0 = 0; k0 < HD; k0 += 64) {
    __syncthreads();
#pragma unroll
    for (int i = 0; i < 4; ++i) {
      gload_lds16(asrc[i] + k0, (char*)As + i * 4096 + wv * 1024);
      gload_lds16(Brole + (size_t)(n0 + trow0 + 32 * i) * HD + k0 + chunk * 8,
                  (char*)Bs + i * 4096 + wv * 1024);
    }
    __syncthreads();
#pragma unroll
    for (int kk = 0; kk < 64; kk += 32) {
      const int krow = lane & 15;
      const int koff = kk + ((lane >> 4) << 3);
      short8 fa[4], fb[4];
#pragma unroll
      for (int mi = 0; mi < 4; ++mi)
        fa[mi] = *(const short8*)&As[(wr * 64 + mi * 16 + krow) * 64 + koff];
#pragma unroll
      for (int ni = 0; ni < 4; ++ni)
        fb[ni] = *(const short8*)&Bs[(wc * 64 + ni * 16 + krow) * 64 + koff];
#pragma unroll
      for (int mi = 0; mi < 4; ++mi)
#pragma unroll
        for (int ni = 0; ni < 4; ++ni)
          acc[mi][ni] = __builtin_amdgcn_mfma_f32_16x16x32_bf16(fa[mi], fb[ni], acc[mi][ni], 0, 0, 0);
    }
  }

  const int ld = dlayer[0];
  const float* bias = biasAll + ((size_t)ld * NR + role) * HD + n0;
#pragma unroll
  for (int ni = 0; ni < 4; ++ni) {
    const int col = wc * 64 + ni * 16 + (lane & 15);
    const float b = bias[col];
#pragma unroll
    for (int mi = 0; mi < 4; ++mi) {
      const int rbase = wr * 64 + mi * 16 + ((lane >> 4) << 2);
#pragma unroll
      for (int j = 0; j < 4; ++j) {
        const int gr = m0 + rbase + j;
        if (gr < mEnd) {
          float val = acc[mi][ni][j] + b;
          if (MODE == 1) {
            val = fmaxf(val, 0.f);
            tout[(size_t)gr * HD + n0 + col] = (short)f2bf(val);
          } else {
            fout[(size_t)perm[gr] * HD + n0 + col] = val;
          }
        }
      }
    }
  }
}

// ---------------- launch ----------------

extern "C" void kernel_launch(void* const* d_in, const int* in_sizes, int n_in,
                              void* d_out, int out_size, void* d_ws, size_t ws_size,
                              hipStream_t stream) {
  const float* v    = (const float*)d_in[0];
  const float* r    = (const float*)d_in[1];
  const int*   rol  = (const int*)d_in[2];
  const float* W    = (const float*)d_in[3];
  const float* Wb   = (const float*)d_in[4];
  const float* U    = (const float*)d_in[5];
  const float* Ub   = (const float*)d_in[6];
  const float* P1   = (const float*)d_in[7];
  const float* P1b  = (const float*)d_in[8];
  const float* P2   = (const float*)d_in[9];
  const float* P2b  = (const float*)d_in[10];
  const int*   dly  = (const int*)d_in[11];
  float* out = (float*)d_out;

  char* ws = (char*)d_ws;
  int* ctrl = (int*)ws;                         // [0..2] cnt, [4..7] offsets, [9..11] cursors
  int* perm = (int*)(ws + 256);                 // E ints
  short* Wbf = (short*)(ws + 131328);           // 4 x NR*HD*HD bf16 (W,U,P1,P2)
  short* Ubf  = Wbf + (size_t)NR * HD * HD;
  short* P1bf = Ubf + (size_t)NR * HD * HD;
  short* P2bf = P1bf + (size_t)NR * HD * HD;
  short* hbuf = (short*)(ws + 6422784);         // E*HD bf16
  short* tbuf = hbuf + (size_t)E_TOT * HD;      // E*HD bf16

  k_init<<<1, 64, 0, stream>>>(ctrl);
  k_hist<<<E_TOT / 256, 256, 0, stream>>>(rol, ctrl);
  k_scan<<<1, 64, 0, stream>>>(ctrl);
  k_scatter<<<E_TOT / 256, 256, 0, stream>>>(rol, ctrl, perm);
  k_convw<<<dim3((NR * HD * HD) / 4 / 256, 4, 1), 256, 0, stream>>>(W, U, P1, P2, dly, Wbf);

  dim3 gg(E_TOT / 128, HD / 128, NR);
  k_g1<<<gg, 256, 0, stream>>>(v, r, Wbf, Ubf, Wb, Ub, dly, ctrl, perm, hbuf);
  k_g23<1><<<gg, 256, 0, stream>>>(hbuf, P1bf, P1b, dly, ctrl, perm, tbuf, nullptr);
  k_g23<2><<<gg, 256, 0, stream>>>(tbuf, P2bf, P2b, dly, ctrl, perm, nullptr, out);

  (void)in_sizes; (void)n_in; (void)out_size; (void)ws_size;
}

// Round 2
// 248.340 us; speedup vs baseline: 1.1120x; 1.1120x over previous
//
#include <hip/hip_runtime.h>
#include <cstdint>
#include <cstddef>

#define E_TOT 32768
#define HD    512
#define NR    3

typedef __attribute__((ext_vector_type(8))) short short8;
typedef __attribute__((ext_vector_type(4))) float f32x4;

static __device__ __forceinline__ unsigned short f2bf(float f) {
  union { float f; unsigned int u; } x; x.f = f;
  unsigned int u = x.u;
  return (unsigned short)((u + 0x7fffu + ((u >> 16) & 1u)) >> 16);  // RNE
}

static __device__ __forceinline__ void gload_lds16(const void* g, void* l) {
  __builtin_amdgcn_global_load_lds(
      (const __attribute__((address_space(1))) unsigned int*)g,
      (__attribute__((address_space(3))) unsigned int*)l, 16, 0, 0);
}

// ---------------- prep kernels ----------------

// one-block: zero + histogram + scan
__global__ void k_sort1(const int* __restrict__ roles, int* __restrict__ ctrl) {
  __shared__ int cnt[NR];
  const int t = threadIdx.x;
  if (t < NR) cnt[t] = 0;
  __syncthreads();
  int c0 = 0, c1 = 0, c2 = 0;
  for (int i = t; i < E_TOT; i += 1024) {
    const int ro = roles[i];
    c0 += (ro == 0); c1 += (ro == 1); c2 += (ro == 2);
  }
  if (c0) atomicAdd(&cnt[0], c0);
  if (c1) atomicAdd(&cnt[1], c1);
  if (c2) atomicAdd(&cnt[2], c2);
  __syncthreads();
  if (t == 0) {
    int off = 0;
#pragma unroll
    for (int r = 0; r < NR; ++r) {
      ctrl[r] = cnt[r]; ctrl[4 + r] = off; ctrl[9 + r] = off; off += cnt[r];
    }
    ctrl[4 + NR] = off;
  }
}

__global__ void k_scatter(const int* __restrict__ roles, int* __restrict__ ctrl,
                          int* __restrict__ perm) {
  int e = blockIdx.x * 256 + threadIdx.x;
  int lane = threadIdx.x & 63;
  int role = roles[e];
#pragma unroll
  for (int r = 0; r < NR; ++r) {
    unsigned long long m = __ballot(role == r);
    if (!m) continue;
    int leader = __ffsll((unsigned long long)m) - 1;
    int base = 0;
    if (lane == leader) base = atomicAdd(&ctrl[9 + r], (int)__popcll(m));
    base = __shfl(base, leader);
    if (role == r) {
      int rank = (int)__popcll(m & ((1ull << lane) - 1ull));
      perm[base + rank] = e;
    }
  }
}

// convert this layer's W,U,P1,P2 slices to bf16: dst = 4 consecutive [NR*HD*HD] arrays
__global__ void k_convw(const float* __restrict__ W, const float* __restrict__ U,
                        const float* __restrict__ P1, const float* __restrict__ P2,
                        const int* __restrict__ dlayer, short* __restrict__ dst) {
  const int per = NR * HD * HD;
  const int which = blockIdx.y;
  const float* src = (which == 0) ? W : (which == 1) ? U : (which == 2) ? P1 : P2;
  src += (size_t)dlayer[0] * per;
  short* d = dst + (size_t)which * per;
  int i = (blockIdx.x * 256 + threadIdx.x) * 4;
  if (i >= per) return;
  float4 v = *(const float4*)(src + i);
  short4 o;
  o.x = (short)f2bf(v.x); o.y = (short)f2bf(v.y);
  o.z = (short)f2bf(v.z); o.w = (short)f2bf(v.w);
  *(short4*)(d + i) = o;
}

// gather-by-perm + convert to bf16, sorted rows. One wave handles one row.
__global__ void k_gather(const float* __restrict__ v, const float* __restrict__ r,
                         const int* __restrict__ perm,
                         short* __restrict__ vbf, short* __restrict__ rbf) {
  const int idx = blockIdx.x * 256 + threadIdx.x;   // E*HD/8 threads
  const int row = idx >> 6;
  const int kc = (idx & 63) << 3;
  const int g = perm[row];
  const float4* pv = (const float4*)(v + (size_t)g * HD + kc);
  const float4* pr = (const float4*)(r + (size_t)g * HD + kc);
  const float4 a0 = pv[0], a1 = pv[1];
  const float4 b0 = pr[0], b1 = pr[1];
  short8 sa, sb;
  sa[0] = (short)f2bf(a0.x); sa[1] = (short)f2bf(a0.y);
  sa[2] = (short)f2bf(a0.z); sa[3] = (short)f2bf(a0.w);
  sa[4] = (short)f2bf(a1.x); sa[5] = (short)f2bf(a1.y);
  sa[6] = (short)f2bf(a1.z); sa[7] = (short)f2bf(a1.w);
  sb[0] = (short)f2bf(b0.x); sb[1] = (short)f2bf(b0.y);
  sb[2] = (short)f2bf(b0.z); sb[3] = (short)f2bf(b0.w);
  sb[4] = (short)f2bf(b1.x); sb[5] = (short)f2bf(b1.y);
  sb[6] = (short)f2bf(b1.z); sb[7] = (short)f2bf(b1.w);
  *(short8*)(vbf + (size_t)row * HD + kc) = sa;
  *(short8*)(rbf + (size_t)row * HD + kc) = sb;
}

// ---------------- GEMM kernels ----------------
// D-frag: col = lane&15, row = (lane>>4)*4 + reg   [m89/m91-verified layout]

// G1: fused dual GEMM, BK=32, 32KB LDS. h = (A_v@W^T + wb)*(A_r@U^T + ub) -> bf16
__global__ __launch_bounds__(256, 2) void k_g1(
    const short* __restrict__ vbf, const short* __restrict__ rbf,
    const short* __restrict__ Wall, const short* __restrict__ Uall,
    const float* __restrict__ Wb, const float* __restrict__ Ub,
    const int* __restrict__ dlayer, const int* __restrict__ ctrl,
    short* __restrict__ hout) {
  __shared__ short Av[128 * 32];
  __shared__ short Ar[128 * 32];
  __shared__ short Bw[128 * 32];
  __shared__ short Bu[128 * 32];

  const int role = blockIdx.z;
  const int mStart = ctrl[4 + role];
  const int mEnd = ctrl[5 + role];
  const int m0 = mStart + blockIdx.x * 128;
  if (m0 >= mEnd) return;
  const int n0 = blockIdx.y * 128;

  const int tid = threadIdx.x;
  const int lane = tid & 63;
  const int wv = tid >> 6;
  const int wr = wv >> 1, wc = wv & 1;
  const int trow = tid >> 2;    // 0..63
  const int chunk = tid & 3;    // 16B chunk within 64B row

  const short* Wrole = Wall + (size_t)role * HD * HD;
  const short* Urole = Uall + (size_t)role * HD * HD;

  const short* aV[2];
  const short* aR[2];
#pragma unroll
  for (int s = 0; s < 2; ++s) {
    int mrow = m0 + trow + 64 * s;
    if (mrow >= mEnd) mrow = mEnd - 1;
    aV[s] = vbf + (size_t)mrow * HD + chunk * 8;
    aR[s] = rbf + (size_t)mrow * HD + chunk * 8;
  }

  f32x4 accv[4][4];
  f32x4 accr[4][4];
#pragma unroll
  for (int a = 0; a < 4; ++a)
#pragma unroll
    for (int b = 0; b < 4; ++b) { accv[a][b] = (f32x4)0.f; accr[a][b] = (f32x4)0.f; }

  for (int k0 = 0; k0 < HD; k0 += 32) {
    __syncthreads();
#pragma unroll
    for (int s = 0; s < 2; ++s) {
      const int brow = n0 + trow + 64 * s;
      gload_lds16(aV[s] + k0, (char*)Av + s * 4096 + wv * 1024);
      gload_lds16(aR[s] + k0, (char*)Ar + s * 4096 + wv * 1024);
      gload_lds16(Wrole + (size_t)brow * HD + k0 + chunk * 8, (char*)Bw + s * 4096 + wv * 1024);
      gload_lds16(Urole + (size_t)brow * HD + k0 + chunk * 8, (char*)Bu + s * 4096 + wv * 1024);
    }
    __syncthreads();
    const int krow = lane & 15;
    const int koff = (lane >> 4) << 3;
    short8 fav[4], far_[4], fbw[4], fbu[4];
#pragma unroll
    for (int mi = 0; mi < 4; ++mi) {
      fav[mi]  = *(const short8*)&Av[(wr * 64 + mi * 16 + krow) * 32 + koff];
      far_[mi] = *(const short8*)&Ar[(wr * 64 + mi * 16 + krow) * 32 + koff];
    }
#pragma unroll
    for (int ni = 0; ni < 4; ++ni) {
      fbw[ni] = *(const short8*)&Bw[(wc * 64 + ni * 16 + krow) * 32 + koff];
      fbu[ni] = *(const short8*)&Bu[(wc * 64 + ni * 16 + krow) * 32 + koff];
    }
#pragma unroll
    for (int mi = 0; mi < 4; ++mi)
#pragma unroll
      for (int ni = 0; ni < 4; ++ni) {
        accv[mi][ni] = __builtin_amdgcn_mfma_f32_16x16x32_bf16(fav[mi], fbw[ni], accv[mi][ni], 0, 0, 0);
        accr[mi][ni] = __builtin_amdgcn_mfma_f32_16x16x32_bf16(far_[mi], fbu[ni], accr[mi][ni], 0, 0, 0);
      }
  }

  const int ld = dlayer[0];
  const float* wb = Wb + ((size_t)ld * NR + role) * HD + n0;
  const float* ub = Ub + ((size_t)ld * NR + role) * HD + n0;
#pragma unroll
  for (int ni = 0; ni < 4; ++ni) {
    const int col = wc * 64 + ni * 16 + (lane & 15);
    const float bw_ = wb[col];
    const float bu_ = ub[col];
#pragma unroll
    for (int mi = 0; mi < 4; ++mi) {
      const int rbase = wr * 64 + mi * 16 + ((lane >> 4) << 2);
#pragma unroll
      for (int j = 0; j < 4; ++j) {
        const int gr = m0 + rbase + j;
        if (gr < mEnd) {
          const float hval = (accv[mi][ni][j] + bw_) * (accr[mi][ni][j] + bu_);
          hout[(size_t)gr * HD + n0 + col] = (short)f2bf(hval);
        }
      }
    }
  }
}

// G2 (MODE 1): t = relu(h@P1^T + b1) -> bf16, sorted rows
// G3 (MODE 2): out[perm[row]] = t@P2^T + b2 -> f32
template <int MODE>
__global__ __launch_bounds__(256, 2) void k_g23(
    const short* __restrict__ Ain, const short* __restrict__ Ball,
    const float* __restrict__ biasAll, const int* __restrict__ dlayer,
    const int* __restrict__ ctrl, const int* __restrict__ perm,
    short* __restrict__ tout, float* __restrict__ fout) {
  __shared__ short As[128 * 64];
  __shared__ short Bs[128 * 64];

  const int role = blockIdx.z;
  const int mStart = ctrl[4 + role];
  const int mEnd = ctrl[5 + role];
  const int m0 = mStart + blockIdx.x * 128;
  if (m0 >= mEnd) return;
  const int n0 = blockIdx.y * 128;

  const int tid = threadIdx.x;
  const int lane = tid & 63;
  const int wv = tid >> 6;
  const int wr = wv >> 1, wc = wv & 1;
  const int trow0 = tid >> 3;   // 0..31
  const int chunk = tid & 7;    // 16B chunk within 128B row

  const short* Brole = Ball + (size_t)role * HD * HD;

  const short* asrc[4];
#pragma unroll
  for (int i = 0; i < 4; ++i) {
    int mrow = m0 + trow0 + 32 * i;
    if (mrow >= mEnd) mrow = mEnd - 1;
    asrc[i] = Ain + (size_t)mrow * HD + chunk * 8;
  }

  f32x4 acc[4][4];
#pragma unroll
  for (int a = 0; a < 4; ++a)
#pragma unroll
    for (int b = 0; b < 4; ++b) acc[a][b] = (f32x4)0.f;

  for (int k0 = 0; k0 < HD; k0 += 64) {
    __syncthreads();
#pragma unroll
    for (int i = 0; i < 4; ++i) {
      gload_lds16(asrc[i] + k0, (char*)As + i * 4096 + wv * 1024);
      gload_lds16(Brole + (size_t)(n0 + trow0 + 32 * i) * HD + k0 + chunk * 8,
                  (char*)Bs + i * 4096 + wv * 1024);
    }
    __syncthreads();
#pragma unroll
    for (int kk = 0; kk < 64; kk += 32) {
      const int krow = lane & 15;
      const int koff = kk + ((lane >> 4) << 3);
      short8 fa[4], fb[4];
#pragma unroll
      for (int mi = 0; mi < 4; ++mi)
        fa[mi] = *(const short8*)&As[(wr * 64 + mi * 16 + krow) * 64 + koff];
#pragma unroll
      for (int ni = 0; ni < 4; ++ni)
        fb[ni] = *(const short8*)&Bs[(wc * 64 + ni * 16 + krow) * 64 + koff];
#pragma unroll
      for (int mi = 0; mi < 4; ++mi)
#pragma unroll
        for (int ni = 0; ni < 4; ++ni)
          acc[mi][ni] = __builtin_amdgcn_mfma_f32_16x16x32_bf16(fa[mi], fb[ni], acc[mi][ni], 0, 0, 0);
    }
  }

  const int ld = dlayer[0];
  const float* bias = biasAll + ((size_t)ld * NR + role) * HD + n0;
  int pg[4][4];
  if (MODE == 2) {
#pragma unroll
    for (int mi = 0; mi < 4; ++mi) {
      const int rbase = wr * 64 + mi * 16 + ((lane >> 4) << 2);
#pragma unroll
      for (int j = 0; j < 4; ++j) {
        const int gr = m0 + rbase + j;
        pg[mi][j] = (gr < mEnd) ? perm[gr] : -1;
      }
    }
  }
#pragma unroll
  for (int ni = 0; ni < 4; ++ni) {
    const int col = wc * 64 + ni * 16 + (lane & 15);
    const float b = bias[col];
#pragma unroll
    for (int mi = 0; mi < 4; ++mi) {
      const int rbase = wr * 64 + mi * 16 + ((lane >> 4) << 2);
#pragma unroll
      for (int j = 0; j < 4; ++j) {
        const int gr = m0 + rbase + j;
        if (MODE == 1) {
          if (gr < mEnd) {
            float val = fmaxf(acc[mi][ni][j] + b, 0.f);
            tout[(size_t)gr * HD + n0 + col] = (short)f2bf(val);
          }
        } else {
          if (pg[mi][j] >= 0) {
            fout[(size_t)pg[mi][j] * HD + n0 + col] = acc[mi][ni][j] + b;
          }
        }
      }
    }
  }
}

// ---------------- launch ----------------

extern "C" void kernel_launch(void* const* d_in, const int* in_sizes, int n_in,
                              void* d_out, int out_size, void* d_ws, size_t ws_size,
                              hipStream_t stream) {
  const float* v    = (const float*)d_in[0];
  const float* r    = (const float*)d_in[1];
  const int*   rol  = (const int*)d_in[2];
  const float* W    = (const float*)d_in[3];
  const float* Wb   = (const float*)d_in[4];
  const float* U    = (const float*)d_in[5];
  const float* Ub   = (const float*)d_in[6];
  const float* P1   = (const float*)d_in[7];
  const float* P1b  = (const float*)d_in[8];
  const float* P2   = (const float*)d_in[9];
  const float* P2b  = (const float*)d_in[10];
  const int*   dly  = (const int*)d_in[11];

  char* ws = (char*)d_ws;
  int* ctrl = (int*)ws;                          // [0..2] cnt, [4..8] offsets, [9..11] cursors
  int* perm = (int*)(ws + 256);                  // E ints
  short* Wbf = (short*)(ws + 131328);            // 4 x NR*HD*HD bf16 (W,U,P1,P2)
  short* Ubf  = Wbf + (size_t)NR * HD * HD;
  short* P1bf = Ubf + (size_t)NR * HD * HD;
  short* P2bf = P1bf + (size_t)NR * HD * HD;
  short* vbf = (short*)(ws + 6422784);           // E*HD bf16 (sorted)
  short* rbf = vbf + (size_t)E_TOT * HD;         // E*HD bf16 (sorted)
  short* tbuf = vbf;                             // aliases vbf (dead after G1)
  short* hbuf = (short*)d_out;                   // front half of d_out (dead before G3 writes)
  float* out = (float*)d_out;

  k_sort1<<<1, 1024, 0, stream>>>(rol, ctrl);
  k_scatter<<<E_TOT / 256, 256, 0, stream>>>(rol, ctrl, perm);
  k_convw<<<dim3((NR * HD * HD) / 4 / 256, 4, 1), 256, 0, stream>>>(W, U, P1, P2, dly, Wbf);
  k_gather<<<E_TOT * HD / 8 / 256, 256, 0, stream>>>(v, r, perm, vbf, rbf);

  dim3 gg(E_TOT / 128, HD / 128, NR);
  k_g1<<<gg, 256, 0, stream>>>(vbf, rbf, Wbf, Ubf, Wb, Ub, dly, ctrl, hbuf);
  k_g23<1><<<gg, 256, 0, stream>>>(hbuf, P1bf, P1b, dly, ctrl, perm, tbuf, nullptr);
  k_g23<2><<<gg, 256, 0, stream>>>(tbuf, P2bf, P2b, dly, ctrl, perm, nullptr, out);

  (void)in_sizes; (void)n_in; (void)out_size; (void)ws_size;
}

// Round 3
// 238.103 us; speedup vs baseline: 1.1598x; 1.0430x over previous
//
#include <hip/hip_runtime.h>
#include <cstdint>
#include <cstddef>

#define E_TOT 32768
#define HD    512
#define NR    3
#define EPAD_MAX 32960          // E_TOT + 3*64 pad
#define NBLK  515               // EPAD_MAX / 64

typedef __attribute__((ext_vector_type(8))) short short8;
typedef __attribute__((ext_vector_type(4))) float f32x4;

static __device__ __forceinline__ unsigned short f2bf(float f) {
  union { float f; unsigned int u; } x; x.f = f;
  unsigned int u = x.u;
  return (unsigned short)((u + 0x7fffu + ((u >> 16) & 1u)) >> 16);  // RNE
}

static __device__ __forceinline__ void gload_lds16(const void* g, void* l) {
  __builtin_amdgcn_global_load_lds(
      (const __attribute__((address_space(1))) unsigned int*)g,
      (__attribute__((address_space(3))) unsigned int*)l, 16, 0, 0);
}

// bijective chunked XCD swizzle for NBLK=515: q=64, r=3
static __device__ __forceinline__ int chunk_swz(int bid) {
  const int xcd = bid & 7;
  const int base = (xcd < 3) ? xcd * 65 : 195 + (xcd - 3) * 64;
  return base + (bid >> 3);
}

// ---------------- prep kernels ----------------

#define AL64(x) (((x) + 63) & ~63)

// one block: histogram + padded scan
__global__ void k_sort1(const int* __restrict__ roles, int* __restrict__ ctrl) {
  __shared__ int cnt[NR];
  const int t = threadIdx.x;
  if (t < NR) cnt[t] = 0;
  __syncthreads();
  int c0 = 0, c1 = 0, c2 = 0;
  for (int i = t; i < E_TOT; i += 1024) {
    const int ro = roles[i];
    c0 += (ro == 0); c1 += (ro == 1); c2 += (ro == 2);
  }
  if (c0) atomicAdd(&cnt[0], c0);
  if (c1) atomicAdd(&cnt[1], c1);
  if (c2) atomicAdd(&cnt[2], c2);
  __syncthreads();
  if (t == 0) {
    const int off0 = 0;
    const int off1 = AL64(cnt[0]);
    const int off2 = AL64(off1 + cnt[1]);
    const int ptot = AL64(off2 + cnt[2]);
    ctrl[0] = cnt[0]; ctrl[1] = cnt[1]; ctrl[2] = cnt[2];
    ctrl[4] = off0; ctrl[5] = off1; ctrl[6] = off2; ctrl[7] = ptot;
    ctrl[9] = off0; ctrl[10] = off1; ctrl[11] = off2;
  }
}

__global__ void k_scatter(const int* __restrict__ roles, int* __restrict__ ctrl,
                          int* __restrict__ perm) {
  int e = blockIdx.x * 256 + threadIdx.x;
  int lane = threadIdx.x & 63;
  int role = roles[e];
#pragma unroll
  for (int r = 0; r < NR; ++r) {
    unsigned long long m = __ballot(role == r);
    if (!m) continue;
    int leader = __ffsll((unsigned long long)m) - 1;
    int base = 0;
    if (lane == leader) base = atomicAdd(&ctrl[9 + r], (int)__popcll(m));
    base = __shfl(base, leader);
    if (role == r) {
      int rank = (int)__popcll(m & ((1ull << lane) - 1ull));
      perm[base + rank] = e;
    }
  }
}

// fill pad slots with duplicates of the role's first entity
__global__ void k_padfill(const int* __restrict__ ctrl, int* __restrict__ perm) {
#pragma unroll
  for (int r = 0; r < NR; ++r) {
    const int start = ctrl[4 + r] + ctrl[r];
    const int end = (r < 2) ? ctrl[5 + r] : EPAD_MAX;
    const int fill = (ctrl[r] > 0) ? perm[ctrl[4 + r]] : 0;
    for (int i = start + (int)threadIdx.x; i < end; i += 256) perm[i] = fill;
  }
}

// convert this layer's W,U,P1,P2 slices to bf16: dst = 4 consecutive [NR*HD*HD] arrays
__global__ void k_convw(const float* __restrict__ W, const float* __restrict__ U,
                        const float* __restrict__ P1, const float* __restrict__ P2,
                        const int* __restrict__ dlayer, short* __restrict__ dst) {
  const int per = NR * HD * HD;
  const int which = blockIdx.y;
  const float* src = (which == 0) ? W : (which == 1) ? U : (which == 2) ? P1 : P2;
  src += (size_t)dlayer[0] * per;
  short* d = dst + (size_t)which * per;
  int i = (blockIdx.x * 256 + threadIdx.x) * 4;
  if (i >= per) return;
  float4 v = *(const float4*)(src + i);
  short4 o;
  o.x = (short)f2bf(v.x); o.y = (short)f2bf(v.y);
  o.z = (short)f2bf(v.z); o.w = (short)f2bf(v.w);
  *(short4*)(d + i) = o;
}

// gather-by-perm + convert to bf16, sorted+padded rows
__global__ void k_gather(const float* __restrict__ v, const float* __restrict__ r,
                         const int* __restrict__ perm,
                         short* __restrict__ vbf, short* __restrict__ rbf) {
  const int idx = blockIdx.x * 256 + threadIdx.x;   // EPAD_MAX*64 threads
  const int row = idx >> 6;
  const int kc = (idx & 63) << 3;
  const int g = perm[row];
  const float4* pv = (const float4*)(v + (size_t)g * HD + kc);
  const float4* pr = (const float4*)(r + (size_t)g * HD + kc);
  const float4 a0 = pv[0], a1 = pv[1];
  const float4 b0 = pr[0], b1 = pr[1];
  short8 sa, sb;
  sa[0] = (short)f2bf(a0.x); sa[1] = (short)f2bf(a0.y);
  sa[2] = (short)f2bf(a0.z); sa[3] = (short)f2bf(a0.w);
  sa[4] = (short)f2bf(a1.x); sa[5] = (short)f2bf(a1.y);
  sa[6] = (short)f2bf(a1.z); sa[7] = (short)f2bf(a1.w);
  sb[0] = (short)f2bf(b0.x); sb[1] = (short)f2bf(b0.y);
  sb[2] = (short)f2bf(b0.z); sb[3] = (short)f2bf(b0.w);
  sb[4] = (short)f2bf(b1.x); sb[5] = (short)f2bf(b1.y);
  sb[6] = (short)f2bf(b1.z); sb[7] = (short)f2bf(b1.w);
  *(short8*)(vbf + (size_t)row * HD + kc) = sa;
  *(short8*)(rbf + (size_t)row * HD + kc) = sb;
}

// ---------------- GEMM kernels ----------------
// BM=64, BN=512 (full N), BK=32, 512 threads = 8 waves (1x8).
// LDS 16B-unit XOR swizzle: LDS[row][s] holds data unit s^(row&3); sources
// pre-swizzled at stage, reads XOR'd  -> conflict-free b128 reads.
// D-frag: col = lane&15, row = (lane>>4)*4 + reg  [m89/m91-verified]

// G1: h = (vbf@W^T + wb) * (rbf@U^T + ub)  -> bf16, sorted+padded rows
__global__ __launch_bounds__(512, 2) void k_g1(
    const short* __restrict__ vbf, const short* __restrict__ rbf,
    const short* __restrict__ Wall, const short* __restrict__ Uall,
    const float* __restrict__ Wb, const float* __restrict__ Ub,
    const int* __restrict__ dlayer, const int* __restrict__ ctrl,
    short* __restrict__ hout) {
  // per buffer (shorts): Av[2048] Ar[2048] Bw[16384] Bu[16384] = 36864 (72KB)
  __shared__ short lds[2][36864];

  const int lb = chunk_swz(blockIdx.x);
  const int ptot = ctrl[7];
  const int m0 = lb * 64;
  if (m0 >= ptot) return;
  const int off1 = ctrl[5], off2 = ctrl[6];
  const int role = (m0 >= off2) ? 2 : (m0 >= off1 ? 1 : 0);

  const int tid = threadIdx.x;
  const int lane = tid & 63;
  const int wv = tid >> 6;

  const short* Wrole = Wall + (size_t)role * HD * HD;
  const short* Urole = Uall + (size_t)role * HD * HD;

  // staging source offsets (pre-swizzled)
  const int sa_row = (tid & 255) >> 2;          // 0..63
  const int sa_s = tid & 3;
  const long aoff = (long)(m0 + sa_row) * HD + 8 * (sa_s ^ (sa_row & 3));
  long boff[4];
#pragma unroll
  for (int i = 0; i < 4; ++i) {
    const int row = i * 128 + (tid >> 2);
    boff[i] = (long)row * HD + 8 * ((tid & 3) ^ (row & 3));
  }

  f32x4 accv[4][4];
  f32x4 accr[4][4];
#pragma unroll
  for (int a = 0; a < 4; ++a)
#pragma unroll
    for (int b = 0; b < 4; ++b) { accv[a][b] = (f32x4)0.f; accr[a][b] = (f32x4)0.f; }

#define STAGE_G1(P, K0)                                                        \
  {                                                                            \
    short* L = lds[P];                                                         \
    if (tid < 256) gload_lds16(vbf + aoff + (K0), L + tid * 8);                \
    else           gload_lds16(rbf + aoff + (K0), L + 2048 + (tid - 256) * 8); \
    _Pragma("unroll")                                                          \
    for (int i = 0; i < 4; ++i) {                                              \
      gload_lds16(Wrole + boff[i] + (K0), L + 4096 + i * 4096 + tid * 8);      \
      gload_lds16(Urole + boff[i] + (K0), L + 20480 + i * 4096 + tid * 8);     \
    }                                                                          \
  }

  const int krow = lane & 15;
  const int uu = ((lane >> 4) ^ (krow & 3)) * 8;

  STAGE_G1(0, 0)
  __syncthreads();
  int p = 0;
  for (int it = 0; it < 16; ++it) {
    if (it < 15) STAGE_G1(p ^ 1, (it + 1) * 32)
    const short* L = lds[p];
    short8 fav[4], far_[4], fbw[4], fbu[4];
#pragma unroll
    for (int mi = 0; mi < 4; ++mi) {
      const int arow = mi * 16 + krow;
      fav[mi]  = *(const short8*)&L[arow * 32 + uu];
      far_[mi] = *(const short8*)&L[2048 + arow * 32 + uu];
    }
#pragma unroll
    for (int ni = 0; ni < 4; ++ni) {
      const int brow = wv * 64 + ni * 16 + krow;
      fbw[ni] = *(const short8*)&L[4096 + brow * 32 + uu];
      fbu[ni] = *(const short8*)&L[20480 + brow * 32 + uu];
    }
#pragma unroll
    for (int mi = 0; mi < 4; ++mi)
#pragma unroll
      for (int ni = 0; ni < 4; ++ni) {
        accv[mi][ni] = __builtin_amdgcn_mfma_f32_16x16x32_bf16(fav[mi], fbw[ni], accv[mi][ni], 0, 0, 0);
        accr[mi][ni] = __builtin_amdgcn_mfma_f32_16x16x32_bf16(far_[mi], fbu[ni], accr[mi][ni], 0, 0, 0);
      }
    __syncthreads();   // drains vmcnt (next buf ready) + frees buf p
    p ^= 1;
  }

  const int ld = dlayer[0];
  const float* wb = Wb + ((size_t)ld * NR + role) * HD;
  const float* ub = Ub + ((size_t)ld * NR + role) * HD;
#pragma unroll
  for (int ni = 0; ni < 4; ++ni) {
    const int col = wv * 64 + ni * 16 + krow;
    const float bw_ = wb[col];
    const float bu_ = ub[col];
#pragma unroll
    for (int mi = 0; mi < 4; ++mi) {
      const int rbase = m0 + mi * 16 + ((lane >> 4) << 2);
#pragma unroll
      for (int j = 0; j < 4; ++j) {
        const float hval = (accv[mi][ni][j] + bw_) * (accr[mi][ni][j] + bu_);
        hout[(size_t)(rbase + j) * HD + col] = (short)f2bf(hval);
      }
    }
  }
}

// G2 (MODE 1): t = relu(h@P1^T + b1) -> bf16, sorted rows
// G3 (MODE 2): out[perm[row]] = t@P2^T + b2 -> f32
template <int MODE>
__global__ __launch_bounds__(512, 2) void k_g23(
    const short* __restrict__ Ain, const short* __restrict__ Ball,
    const float* __restrict__ biasAll, const int* __restrict__ dlayer,
    const int* __restrict__ ctrl, const int* __restrict__ perm,
    short* __restrict__ tout, float* __restrict__ fout) {
  // per buffer (shorts): A[2048] B[16384] = 18432 (36KB)
  __shared__ short lds[2][18432];

  const int lb = chunk_swz(blockIdx.x);
  const int ptot = ctrl[7];
  const int m0 = lb * 64;
  if (m0 >= ptot) return;
  const int off1 = ctrl[5], off2 = ctrl[6];
  const int role = (m0 >= off2) ? 2 : (m0 >= off1 ? 1 : 0);

  const int tid = threadIdx.x;
  const int lane = tid & 63;
  const int wv = tid >> 6;

  const short* Brole = Ball + (size_t)role * HD * HD;

  const int sa_row = (tid & 255) >> 2;
  const int sa_s = tid & 3;
  const long aoff = (long)(m0 + sa_row) * HD + 8 * (sa_s ^ (sa_row & 3));
  long boff[4];
#pragma unroll
  for (int i = 0; i < 4; ++i) {
    const int row = i * 128 + (tid >> 2);
    boff[i] = (long)row * HD + 8 * ((tid & 3) ^ (row & 3));
  }

  f32x4 acc[4][4];
#pragma unroll
  for (int a = 0; a < 4; ++a)
#pragma unroll
    for (int b = 0; b < 4; ++b) acc[a][b] = (f32x4)0.f;

#define STAGE_G23(P, K0)                                                      \
  {                                                                           \
    short* L = lds[P];                                                        \
    if (tid < 256) gload_lds16(Ain + aoff + (K0), L + tid * 8);               \
    _Pragma("unroll")                                                         \
    for (int i = 0; i < 4; ++i)                                               \
      gload_lds16(Brole + boff[i] + (K0), L + 2048 + i * 4096 + tid * 8);     \
  }

  const int krow = lane & 15;
  const int uu = ((lane >> 4) ^ (krow & 3)) * 8;

  STAGE_G23(0, 0)
  __syncthreads();
  int p = 0;
  for (int it = 0; it < 16; ++it) {
    if (it < 15) STAGE_G23(p ^ 1, (it + 1) * 32)
    const short* L = lds[p];
    short8 fa[4], fb[4];
#pragma unroll
    for (int mi = 0; mi < 4; ++mi)
      fa[mi] = *(const short8*)&L[(mi * 16 + krow) * 32 + uu];
#pragma unroll
    for (int ni = 0; ni < 4; ++ni)
      fb[ni] = *(const short8*)&L[2048 + (wv * 64 + ni * 16 + krow) * 32 + uu];
#pragma unroll
    for (int mi = 0; mi < 4; ++mi)
#pragma unroll
      for (int ni = 0; ni < 4; ++ni)
        acc[mi][ni] = __builtin_amdgcn_mfma_f32_16x16x32_bf16(fa[mi], fb[ni], acc[mi][ni], 0, 0, 0);
    __syncthreads();
    p ^= 1;
  }

  const int ld = dlayer[0];
  const float* bias = biasAll + ((size_t)ld * NR + role) * HD;
  int pg[4][4];
  if (MODE == 2) {
#pragma unroll
    for (int mi = 0; mi < 4; ++mi) {
      const int rbase = m0 + mi * 16 + ((lane >> 4) << 2);
#pragma unroll
      for (int j = 0; j < 4; ++j) pg[mi][j] = perm[rbase + j];
    }
  }
#pragma unroll
  for (int ni = 0; ni < 4; ++ni) {
    const int col = wv * 64 + ni * 16 + krow;
    const float b = bias[col];
#pragma unroll
    for (int mi = 0; mi < 4; ++mi) {
      const int rbase = m0 + mi * 16 + ((lane >> 4) << 2);
#pragma unroll
      for (int j = 0; j < 4; ++j) {
        float val = acc[mi][ni][j] + b;
        if (MODE == 1) {
          val = fmaxf(val, 0.f);
          tout[(size_t)(rbase + j) * HD + col] = (short)f2bf(val);
        } else {
          fout[(size_t)pg[mi][j] * HD + col] = val;
        }
      }
    }
  }
}

// ---------------- launch ----------------

extern "C" void kernel_launch(void* const* d_in, const int* in_sizes, int n_in,
                              void* d_out, int out_size, void* d_ws, size_t ws_size,
                              hipStream_t stream) {
  const float* v    = (const float*)d_in[0];
  const float* r    = (const float*)d_in[1];
  const int*   rol  = (const int*)d_in[2];
  const float* W    = (const float*)d_in[3];
  const float* Wb   = (const float*)d_in[4];
  const float* U    = (const float*)d_in[5];
  const float* Ub   = (const float*)d_in[6];
  const float* P1   = (const float*)d_in[7];
  const float* P1b  = (const float*)d_in[8];
  const float* P2   = (const float*)d_in[9];
  const float* P2b  = (const float*)d_in[10];
  const int*   dly  = (const int*)d_in[11];

  char* ws = (char*)d_ws;
  int* ctrl = (int*)ws;                          // 256 B
  int* perm = (int*)(ws + 256);                  // EPAD_MAX ints -> ends 132096
  short* Wbf = (short*)(ws + 132096);            // 4 x NR*HD*HD bf16
  short* Ubf  = Wbf + (size_t)NR * HD * HD;
  short* P1bf = Ubf + (size_t)NR * HD * HD;
  short* P2bf = P1bf + (size_t)NR * HD * HD;
  short* vbf = (short*)(ws + 6423552);           // EPAD_MAX*HD bf16 (sorted)
  short* rbf = vbf + (size_t)EPAD_MAX * HD;      // EPAD_MAX*HD bf16 (sorted)
  short* tbuf = vbf;                             // alias (vbf dead after G1)
  short* hbuf = (short*)d_out;                   // front of d_out (dead before G3 writes)
  float* out = (float*)d_out;

  k_sort1<<<1, 1024, 0, stream>>>(rol, ctrl);
  k_scatter<<<E_TOT / 256, 256, 0, stream>>>(rol, ctrl, perm);
  k_padfill<<<1, 256, 0, stream>>>(ctrl, perm);
  k_convw<<<dim3((NR * HD * HD) / 4 / 256, 4, 1), 256, 0, stream>>>(W, U, P1, P2, dly, Wbf);
  k_gather<<<EPAD_MAX * 64 / 256, 256, 0, stream>>>(v, r, perm, vbf, rbf);

  k_g1<<<NBLK, 512, 0, stream>>>(vbf, rbf, Wbf, Ubf, Wb, Ub, dly, ctrl, hbuf);
  k_g23<1><<<NBLK, 512, 0, stream>>>(hbuf, P1bf, P1b, dly, ctrl, perm, tbuf, nullptr);
  k_g23<2><<<NBLK, 512, 0, stream>>>(tbuf, P2bf, P2b, dly, ctrl, perm, nullptr, out);

  (void)in_sizes; (void)n_in; (void)out_size; (void)ws_size;
}